// Round 5
// baseline (183.332 us; speedup 1.0000x reference)
//
#include <hip/hip_runtime.h>
#include <math.h>

#define N_ROWS 4096
#define D_DIM  256
#define INV_T  (1.0f / 0.07f)

typedef _Float16 half8 __attribute__((ext_vector_type(8)));
typedef _Float16 half4 __attribute__((ext_vector_type(4)));
typedef float    f32x4 __attribute__((ext_vector_type(4)));

#define GLOAD_LDS(gp, lp) \
    __builtin_amdgcn_global_load_lds( \
        (const __attribute__((address_space(1))) void*)(gp), \
        (__attribute__((address_space(3))) void*)(lp), 16, 0, 0)

// ---------------------------------------------------------------------------
// K1: row-normalize features -> fp16 (one wave per row) + zero accum.
// ---------------------------------------------------------------------------
__global__ __launch_bounds__(256) void normalize_k(const float* __restrict__ f,
                                                   _Float16* __restrict__ fnh,
                                                   float* __restrict__ accum) {
    const int t   = threadIdx.x;
    const int gid = blockIdx.x * 256 + t;
    if (gid < 3 * N_ROWS) accum[gid] = 0.0f;

    const int lane = t & 63;
    const int row  = blockIdx.x * 4 + (t >> 6);
    float4 v = ((const float4*)(f + (size_t)row * D_DIM))[lane];
    float s = v.x * v.x + v.y * v.y + v.z * v.z + v.w * v.w;
    #pragma unroll
    for (int off = 32; off > 0; off >>= 1) s += __shfl_xor(s, off, 64);
    float rn = 1.0f / fmaxf(sqrtf(s), 1e-8f);
    half4 h;
    h.x = (_Float16)(v.x * rn);
    h.y = (_Float16)(v.y * rn);
    h.z = (_Float16)(v.z * rn);
    h.w = (_Float16)(v.w * rn);
    *(half4*)(fnh + (size_t)row * D_DIM + lane * 4) = h;
}

// ---------------------------------------------------------------------------
// K2a: MFMA cosim -> cs (fp16, 32 MB) in workspace.
// Tile 128x128, BK=64, 4 waves; XOR-swizzled LDS (0 bank conflicts, round 3).
// Epilogue: acc -> LDS (swizzled) -> coalesced half8 global stores.
// ---------------------------------------------------------------------------
__global__ __launch_bounds__(256, 4) void gemm_cs_k(const _Float16* __restrict__ fnh,
                                                    _Float16* __restrict__ cs) {
    __shared__ __align__(16) _Float16 lds[128 * 128];  // 32 KB
    _Float16* As = lds;
    _Float16* Bs = lds + 128 * 64;

    const int t    = threadIdx.x;
    const int lane = t & 63;
    const int w    = t >> 6;
    const int wr   = w >> 1;
    const int wc   = w & 1;
    const int i0   = blockIdx.y * 128;
    const int j0   = blockIdx.x * 128;
    const int l15  = lane & 15;
    const int grp  = lane >> 4;

    const int srow = t >> 3;
    const int sseg = ((t & 7) ^ ((t >> 3) & 7)) * 8;

    f32x4 acc[4][4];  // [jt][it]
    #pragma unroll
    for (int a = 0; a < 4; ++a)
        #pragma unroll
        for (int b = 0; b < 4; ++b)
            acc[a][b] = (f32x4){0.f, 0.f, 0.f, 0.f};

    for (int k0 = 0; k0 < D_DIM; k0 += 64) {
        #pragma unroll
        for (int q = 0; q < 4; ++q) {
            GLOAD_LDS(fnh + (size_t)(i0 + q * 32 + srow) * D_DIM + k0 + sseg,
                      &As[q * 2048 + w * 512]);
            GLOAD_LDS(fnh + (size_t)(j0 + q * 32 + srow) * D_DIM + k0 + sseg,
                      &Bs[q * 2048 + w * 512]);
        }
        __syncthreads();

        #pragma unroll
        for (int kk = 0; kk < 2; ++kk) {
            const int swz = ((kk * 4 + grp) ^ (l15 & 7)) * 8;
            half8 aj[4], bi[4];
            #pragma unroll
            for (int jt = 0; jt < 4; ++jt)
                aj[jt] = *(const half8*)&Bs[(wc * 64 + jt * 16 + l15) * 64 + swz];
            #pragma unroll
            for (int it = 0; it < 4; ++it)
                bi[it] = *(const half8*)&As[(wr * 64 + it * 16 + l15) * 64 + swz];
            #pragma unroll
            for (int jt = 0; jt < 4; ++jt)
                #pragma unroll
                for (int it = 0; it < 4; ++it)
                    acc[jt][it] = __builtin_amdgcn_mfma_f32_16x16x32_f16(
                        aj[jt], bi[it], acc[jt][it], 0, 0, 0);
        }
        __syncthreads();
    }

    // acc -> LDS as fp16, 16B-granule XOR swizzle (g ^ (row&15)).
    #pragma unroll
    for (int it = 0; it < 4; ++it) {
        const int row = wr * 64 + it * 16 + l15;
        #pragma unroll
        for (int jt = 0; jt < 4; ++jt) {
            half4 h;
            h.x = (_Float16)(acc[jt][it][0] * INV_T);
            h.y = (_Float16)(acc[jt][it][1] * INV_T);
            h.z = (_Float16)(acc[jt][it][2] * INV_T);
            h.w = (_Float16)(acc[jt][it][3] * INV_T);
            const int g   = wc * 8 + jt * 2 + (grp >> 1);
            const int off = ((g ^ l15) << 4) | ((grp & 1) << 3);
            *(half4*)((char*)lds + row * 256 + off) = h;
        }
    }
    __syncthreads();

    // LDS -> global cs, coalesced: 16 lanes cover one row's 256 B.
    const int sr = t >> 4;   // 0..15
    const int g  = t & 15;
    #pragma unroll
    for (int s = 0; s < 8; ++s) {
        const int r = s * 16 + sr;
        half8 v = *(const half8*)((const char*)lds + r * 256 + (((g ^ (r & 15)) << 4)));
        *(half8*)(cs + (size_t)(i0 + r) * N_ROWS + j0 + g * 8) = v;
    }
}

// ---------------------------------------------------------------------------
// K2b: mask streaming. One wave per HALF-row (8192 waves = 32 waves/CU).
// No LDS, coalesced 1KB/instr mask loads, double-buffered batch-4 pipeline,
// one 6-level shuffle reduce per wave, 3 atomics per wave.
// ---------------------------------------------------------------------------
__global__ __launch_bounds__(256, 4) void stream_k(const _Float16* __restrict__ cs,
                                                   const float* __restrict__ pm,
                                                   const float* __restrict__ nm,
                                                   float* __restrict__ accum) {
    const int t    = threadIdx.x;
    const int lane = t & 63;
    const int wid  = blockIdx.x * 4 + (t >> 6);
    const int i    = wid >> 1;
    const int hf   = wid & 1;          // which half of the row
    const int base = hf * 512 + lane;  // float4 / half4 index into the row

    const float4* pmr = (const float4*)(pm + (size_t)i * N_ROWS) + base;
    const float4* nmr = (const float4*)(nm + (size_t)i * N_ROWS) + base;
    const half4*  csr = (const half4*)(cs + (size_t)i * N_ROWS) + base;

    float4 pA[4], nA[4]; half4 cA[4];
    #pragma unroll
    for (int u = 0; u < 4; ++u) {
        pA[u] = pmr[u * 64];
        nA[u] = nmr[u * 64];
        cA[u] = csr[u * 64];
    }

    float negp = 0.f, posp = 0.f, np = 0.f;
    #pragma unroll
    for (int blk = 0; blk < 2; ++blk) {
        float4 pB[4], nB[4]; half4 cB[4];
        if (blk == 0) {
            #pragma unroll
            for (int u = 0; u < 4; ++u) {
                pB[u] = pmr[(u + 4) * 64];
                nB[u] = nmr[(u + 4) * 64];
                cB[u] = csr[(u + 4) * 64];
            }
        }
        #pragma unroll
        for (int u = 0; u < 4; ++u) {
            const int jb = hf * 2048 + (blk * 4 + u) * 256 + lane * 4;
            float pme[4] = {pA[u].x, pA[u].y, pA[u].z, pA[u].w};
            float nme[4] = {nA[u].x, nA[u].y, nA[u].z, nA[u].w};
            float cse[4] = {(float)cA[u].x, (float)cA[u].y,
                            (float)cA[u].z, (float)cA[u].w};
            #pragma unroll
            for (int e = 0; e < 4; ++e) {
                float keep = (jb + e == i) ? 0.f : 1.f;
                float p  = pme[e] * keep;
                float nv = nme[e] * keep;
                negp = fmaf(__expf(cse[e]), nv, negp);
                posp = fmaf(cse[e], p, posp);
                np  += p;
            }
        }
        if (blk == 0) {
            #pragma unroll
            for (int u = 0; u < 4; ++u) { pA[u] = pB[u]; nA[u] = nB[u]; cA[u] = cB[u]; }
        }
    }

    #pragma unroll
    for (int off = 1; off < 64; off <<= 1) {
        negp += __shfl_xor(negp, off, 64);
        posp += __shfl_xor(posp, off, 64);
        np   += __shfl_xor(np,   off, 64);
    }
    if (lane == 0) {
        atomicAdd(&accum[i], negp);
        atomicAdd(&accum[N_ROWS + i], posp);
        atomicAdd(&accum[2 * N_ROWS + i], np);
    }
}

// ---------------------------------------------------------------------------
// Fallback (ws too small for cs): round-4 fused kernel, unchanged.
// ---------------------------------------------------------------------------
__global__ __launch_bounds__(256, 4) void fused_k(const _Float16* __restrict__ fnh,
                                                  const float* __restrict__ pm,
                                                  const float* __restrict__ nm,
                                                  float* __restrict__ accum) {
    __shared__ __align__(16) _Float16 lds[128 * 128];
    _Float16* As = lds;
    _Float16* Bs = lds + 128 * 64;

    const int t    = threadIdx.x;
    const int lane = t & 63;
    const int w    = t >> 6;
    const int wr   = w >> 1;
    const int wc   = w & 1;
    const int i0   = blockIdx.y * 128;
    const int j0   = blockIdx.x * 128;
    const int l15  = lane & 15;
    const int grp  = lane >> 4;
    const int srow = t >> 3;
    const int sseg = ((t & 7) ^ ((t >> 3) & 7)) * 8;

    f32x4 acc[4][4];
    #pragma unroll
    for (int a = 0; a < 4; ++a)
        #pragma unroll
        for (int b = 0; b < 4; ++b)
            acc[a][b] = (f32x4){0.f, 0.f, 0.f, 0.f};

    for (int k0 = 0; k0 < D_DIM; k0 += 64) {
        #pragma unroll
        for (int q = 0; q < 4; ++q) {
            GLOAD_LDS(fnh + (size_t)(i0 + q * 32 + srow) * D_DIM + k0 + sseg,
                      &As[q * 2048 + w * 512]);
            GLOAD_LDS(fnh + (size_t)(j0 + q * 32 + srow) * D_DIM + k0 + sseg,
                      &Bs[q * 2048 + w * 512]);
        }
        __syncthreads();
        #pragma unroll
        for (int kk = 0; kk < 2; ++kk) {
            const int swz = ((kk * 4 + grp) ^ (l15 & 7)) * 8;
            half8 aj[4], bi[4];
            #pragma unroll
            for (int jt = 0; jt < 4; ++jt)
                aj[jt] = *(const half8*)&Bs[(wc * 64 + jt * 16 + l15) * 64 + swz];
            #pragma unroll
            for (int it = 0; it < 4; ++it)
                bi[it] = *(const half8*)&As[(wr * 64 + it * 16 + l15) * 64 + swz];
            #pragma unroll
            for (int jt = 0; jt < 4; ++jt)
                #pragma unroll
                for (int it = 0; it < 4; ++it)
                    acc[jt][it] = __builtin_amdgcn_mfma_f32_16x16x32_f16(
                        aj[jt], bi[it], acc[jt][it], 0, 0, 0);
        }
        __syncthreads();
    }

    #pragma unroll
    for (int it = 0; it < 4; ++it) {
        const int row = wr * 64 + it * 16 + l15;
        #pragma unroll
        for (int jt = 0; jt < 4; ++jt) {
            half4 h;
            h.x = (_Float16)(acc[jt][it][0] * INV_T);
            h.y = (_Float16)(acc[jt][it][1] * INV_T);
            h.z = (_Float16)(acc[jt][it][2] * INV_T);
            h.w = (_Float16)(acc[jt][it][3] * INV_T);
            const int g   = wc * 8 + jt * 2 + (grp >> 1);
            const int off = ((g ^ l15) << 4) | ((grp & 1) << 3);
            *(half4*)((char*)lds + row * 256 + off) = h;
        }
    }
    __syncthreads();

    const int lrow8 = t >> 5;
    const int lcol  = t & 31;
    const int gsw   = lcol >> 1;
    const int soff  = (lcol & 1) << 3;
    #pragma unroll
    for (int s = 0; s < 16; ++s) {
        const int r  = s * 8 + lrow8;
        const int i  = i0 + r;
        const int jb = j0 + lcol * 4;
        float4 pmv = *(const float4*)(pm + (size_t)i * N_ROWS + jb);
        float4 nmv = *(const float4*)(nm + (size_t)i * N_ROWS + jb);
        half4 h = *(const half4*)((const char*)lds + r * 256 +
                                  (((gsw ^ (r & 15)) << 4) | soff));
        float cse[4] = {(float)h.x, (float)h.y, (float)h.z, (float)h.w};
        float pme[4] = {pmv.x, pmv.y, pmv.z, pmv.w};
        float nme[4] = {nmv.x, nmv.y, nmv.z, nmv.w};
        float negp = 0.f, posp = 0.f, np = 0.f;
        #pragma unroll
        for (int e = 0; e < 4; ++e) {
            float keep = (i == jb + e) ? 0.f : 1.f;
            float p  = pme[e] * keep;
            float nv = nme[e] * keep;
            negp = fmaf(__expf(cse[e]), nv, negp);
            posp = fmaf(cse[e], p, posp);
            np  += p;
        }
        #pragma unroll
        for (int off = 1; off < 32; off <<= 1) {
            negp += __shfl_xor(negp, off, 64);
            posp += __shfl_xor(posp, off, 64);
            np   += __shfl_xor(np,   off, 64);
        }
        if (lcol == 0) {
            atomicAdd(&accum[i], negp);
            atomicAdd(&accum[N_ROWS + i], posp);
            atomicAdd(&accum[2 * N_ROWS + i], np);
        }
    }
}

// ---------------------------------------------------------------------------
// K3: final reduction over rows -> scalar loss
// ---------------------------------------------------------------------------
__global__ __launch_bounds__(256) void final_k(const float* __restrict__ accum,
                                               float* __restrict__ out) {
    const int t = threadIdx.x;
    float s = 0.f;
    for (int i = t; i < N_ROWS; i += 256) {
        float neg  = accum[i];
        float posc = accum[N_ROWS + i];
        float np   = accum[2 * N_ROWS + i];
        float term = (np > 0.f) ? (posc - np * logf(fmaxf(neg, 1e-30f))) / np : 0.f;
        s += term;
    }
    #pragma unroll
    for (int off = 32; off > 0; off >>= 1) s += __shfl_xor(s, off, 64);
    __shared__ float wsum[4];
    if ((t & 63) == 0) wsum[t >> 6] = s;
    __syncthreads();
    if (t == 0) {
        float tot = wsum[0] + wsum[1] + wsum[2] + wsum[3];
        out[0] = -tot / (float)N_ROWS;
    }
}

// ---------------------------------------------------------------------------
extern "C" void kernel_launch(void* const* d_in, const int* in_sizes, int n_in,
                              void* d_out, int out_size, void* d_ws, size_t ws_size,
                              hipStream_t stream) {
    const float* feat = (const float*)d_in[0];
    const float* pm   = (const float*)d_in[1];
    const float* nm   = (const float*)d_in[2];
    float* out = (float*)d_out;

    _Float16* fnh = (_Float16*)d_ws;                          // 2 MB
    float* accum  = (float*)(fnh + (size_t)N_ROWS * D_DIM);   // 48 KB
    _Float16* cs  = (_Float16*)(accum + 3 * N_ROWS);          // 32 MB

    const size_t need = (size_t)N_ROWS * D_DIM * 2 + 3 * N_ROWS * 4
                      + (size_t)N_ROWS * N_ROWS * 2;

    normalize_k<<<N_ROWS / 4, 256, 0, stream>>>(feat, fnh, accum);

    if (ws_size >= need) {
        dim3 grid(N_ROWS / 128, N_ROWS / 128);
        gemm_cs_k<<<grid, 256, 0, stream>>>(fnh, cs);
        stream_k<<<(2 * N_ROWS) / 4, 256, 0, stream>>>(cs, pm, nm, accum);
    } else {
        dim3 grid(N_ROWS / 128, N_ROWS / 128);
        fused_k<<<grid, 256, 0, stream>>>(fnh, pm, nm, accum);
    }

    final_k<<<1, 256, 0, stream>>>(accum, out);
}

// Round 6
// 181.547 us; speedup vs baseline: 1.0098x; 1.0098x over previous
//
#include <hip/hip_runtime.h>
#include <math.h>

#define N_ROWS 4096
#define D_DIM  256
#define INV_T  (1.0f / 0.07f)

typedef _Float16 half8 __attribute__((ext_vector_type(8)));
typedef _Float16 half4 __attribute__((ext_vector_type(4)));
typedef float    f32x4 __attribute__((ext_vector_type(4)));

#define GLOAD_LDS(gp, lp) \
    __builtin_amdgcn_global_load_lds( \
        (const __attribute__((address_space(1))) void*)(gp), \
        (__attribute__((address_space(3))) void*)(lp), 16, 0, 0)

// ---------------------------------------------------------------------------
// K1: row-normalize features -> fp16 (one wave per row) + zero accum.
// ---------------------------------------------------------------------------
__global__ __launch_bounds__(256) void normalize_k(const float* __restrict__ f,
                                                   _Float16* __restrict__ fnh,
                                                   float* __restrict__ accum) {
    const int t   = threadIdx.x;
    const int gid = blockIdx.x * 256 + t;
    if (gid < 3 * N_ROWS) accum[gid] = 0.0f;

    const int lane = t & 63;
    const int row  = blockIdx.x * 4 + (t >> 6);
    float4 v = ((const float4*)(f + (size_t)row * D_DIM))[lane];
    float s = v.x * v.x + v.y * v.y + v.z * v.z + v.w * v.w;
    #pragma unroll
    for (int off = 32; off > 0; off >>= 1) s += __shfl_xor(s, off, 64);
    float rn = 1.0f / fmaxf(sqrtf(s), 1e-8f);
    half4 h;
    h.x = (_Float16)(v.x * rn);
    h.y = (_Float16)(v.y * rn);
    h.z = (_Float16)(v.z * rn);
    h.w = (_Float16)(v.w * rn);
    *(half4*)(fnh + (size_t)row * D_DIM + lane * 4) = h;
}

// ---------------------------------------------------------------------------
// K2a: MFMA cosim -> cs (fp16, 32 MB) in workspace. (unchanged from round 5)
// ---------------------------------------------------------------------------
__global__ __launch_bounds__(256, 4) void gemm_cs_k(const _Float16* __restrict__ fnh,
                                                    _Float16* __restrict__ cs) {
    __shared__ __align__(16) _Float16 lds[128 * 128];  // 32 KB
    _Float16* As = lds;
    _Float16* Bs = lds + 128 * 64;

    const int t    = threadIdx.x;
    const int lane = t & 63;
    const int w    = t >> 6;
    const int wr   = w >> 1;
    const int wc   = w & 1;
    const int i0   = blockIdx.y * 128;
    const int j0   = blockIdx.x * 128;
    const int l15  = lane & 15;
    const int grp  = lane >> 4;

    const int srow = t >> 3;
    const int sseg = ((t & 7) ^ ((t >> 3) & 7)) * 8;

    f32x4 acc[4][4];  // [jt][it]
    #pragma unroll
    for (int a = 0; a < 4; ++a)
        #pragma unroll
        for (int b = 0; b < 4; ++b)
            acc[a][b] = (f32x4){0.f, 0.f, 0.f, 0.f};

    for (int k0 = 0; k0 < D_DIM; k0 += 64) {
        #pragma unroll
        for (int q = 0; q < 4; ++q) {
            GLOAD_LDS(fnh + (size_t)(i0 + q * 32 + srow) * D_DIM + k0 + sseg,
                      &As[q * 2048 + w * 512]);
            GLOAD_LDS(fnh + (size_t)(j0 + q * 32 + srow) * D_DIM + k0 + sseg,
                      &Bs[q * 2048 + w * 512]);
        }
        __syncthreads();

        #pragma unroll
        for (int kk = 0; kk < 2; ++kk) {
            const int swz = ((kk * 4 + grp) ^ (l15 & 7)) * 8;
            half8 aj[4], bi[4];
            #pragma unroll
            for (int jt = 0; jt < 4; ++jt)
                aj[jt] = *(const half8*)&Bs[(wc * 64 + jt * 16 + l15) * 64 + swz];
            #pragma unroll
            for (int it = 0; it < 4; ++it)
                bi[it] = *(const half8*)&As[(wr * 64 + it * 16 + l15) * 64 + swz];
            #pragma unroll
            for (int jt = 0; jt < 4; ++jt)
                #pragma unroll
                for (int it = 0; it < 4; ++it)
                    acc[jt][it] = __builtin_amdgcn_mfma_f32_16x16x32_f16(
                        aj[jt], bi[it], acc[jt][it], 0, 0, 0);
        }
        __syncthreads();
    }

    #pragma unroll
    for (int it = 0; it < 4; ++it) {
        const int row = wr * 64 + it * 16 + l15;
        #pragma unroll
        for (int jt = 0; jt < 4; ++jt) {
            half4 h;
            h.x = (_Float16)(acc[jt][it][0] * INV_T);
            h.y = (_Float16)(acc[jt][it][1] * INV_T);
            h.z = (_Float16)(acc[jt][it][2] * INV_T);
            h.w = (_Float16)(acc[jt][it][3] * INV_T);
            const int g   = wc * 8 + jt * 2 + (grp >> 1);
            const int off = ((g ^ l15) << 4) | ((grp & 1) << 3);
            *(half4*)((char*)lds + row * 256 + off) = h;
        }
    }
    __syncthreads();

    const int sr = t >> 4;
    const int g  = t & 15;
    #pragma unroll
    for (int s = 0; s < 8; ++s) {
        const int r = s * 16 + sr;
        half8 v = *(const half8*)((const char*)lds + r * 256 + (((g ^ (r & 15)) << 4)));
        *(half8*)(cs + (size_t)(i0 + r) * N_ROWS + j0 + g * 8) = v;
    }
}

// ---------------------------------------------------------------------------
// K2b: mask streaming, round 6: one wave per QUARTER-row (16384 waves).
// All 12 loads per lane issued up-front (independent, immediate offsets
// <= 3072 B), payload held in ~40 VGPRs -> deep pipeline the compiler can't
// serialize. No launch_bounds min-waves hint (round-5's VGPR=32 sank loads).
// ---------------------------------------------------------------------------
__global__ __launch_bounds__(256) void stream_k(const _Float16* __restrict__ cs,
                                                const float* __restrict__ pm,
                                                const float* __restrict__ nm,
                                                float* __restrict__ accum) {
    const int t    = threadIdx.x;
    const int lane = t & 63;
    const int wid  = blockIdx.x * 4 + (t >> 6);   // 0..16383
    const int i    = wid >> 2;
    const int base = (wid & 3) * 256 + lane;      // float4/half4 index in row

    const float4* pmr = (const float4*)(pm + (size_t)i * N_ROWS) + base;
    const float4* nmr = (const float4*)(nm + (size_t)i * N_ROWS) + base;
    const half4*  csr = (const half4*)(cs + (size_t)i * N_ROWS) + base;

    float4 p[4], n[4];
    half4  c[4];
    #pragma unroll
    for (int u = 0; u < 4; ++u) p[u] = pmr[u * 64];
    #pragma unroll
    for (int u = 0; u < 4; ++u) n[u] = nmr[u * 64];
    #pragma unroll
    for (int u = 0; u < 4; ++u) c[u] = csr[u * 64];

    float negp = 0.f, posp = 0.f, np = 0.f;
    #pragma unroll
    for (int u = 0; u < 4; ++u) {
        const int jb = (base + u * 64) << 2;
        float pe[4] = {p[u].x, p[u].y, p[u].z, p[u].w};
        float ne[4] = {n[u].x, n[u].y, n[u].z, n[u].w};
        float ce[4] = {(float)c[u].x, (float)c[u].y,
                       (float)c[u].z, (float)c[u].w};
        #pragma unroll
        for (int e = 0; e < 4; ++e) {
            float keep = (jb + e == i) ? 0.f : 1.f;
            float pp = pe[e] * keep;
            float nv = ne[e] * keep;
            negp = fmaf(__expf(ce[e]), nv, negp);
            posp = fmaf(ce[e], pp, posp);
            np  += pp;
        }
    }

    #pragma unroll
    for (int off = 1; off < 64; off <<= 1) {
        negp += __shfl_xor(negp, off, 64);
        posp += __shfl_xor(posp, off, 64);
        np   += __shfl_xor(np,   off, 64);
    }
    if (lane == 0) {
        atomicAdd(&accum[i], negp);
        atomicAdd(&accum[N_ROWS + i], posp);
        atomicAdd(&accum[2 * N_ROWS + i], np);
    }
}

// ---------------------------------------------------------------------------
// Fallback (ws too small for cs): round-4 fused kernel, unchanged.
// ---------------------------------------------------------------------------
__global__ __launch_bounds__(256, 4) void fused_k(const _Float16* __restrict__ fnh,
                                                  const float* __restrict__ pm,
                                                  const float* __restrict__ nm,
                                                  float* __restrict__ accum) {
    __shared__ __align__(16) _Float16 lds[128 * 128];
    _Float16* As = lds;
    _Float16* Bs = lds + 128 * 64;

    const int t    = threadIdx.x;
    const int lane = t & 63;
    const int w    = t >> 6;
    const int wr   = w >> 1;
    const int wc   = w & 1;
    const int i0   = blockIdx.y * 128;
    const int j0   = blockIdx.x * 128;
    const int l15  = lane & 15;
    const int grp  = lane >> 4;
    const int srow = t >> 3;
    const int sseg = ((t & 7) ^ ((t >> 3) & 7)) * 8;

    f32x4 acc[4][4];
    #pragma unroll
    for (int a = 0; a < 4; ++a)
        #pragma unroll
        for (int b = 0; b < 4; ++b)
            acc[a][b] = (f32x4){0.f, 0.f, 0.f, 0.f};

    for (int k0 = 0; k0 < D_DIM; k0 += 64) {
        #pragma unroll
        for (int q = 0; q < 4; ++q) {
            GLOAD_LDS(fnh + (size_t)(i0 + q * 32 + srow) * D_DIM + k0 + sseg,
                      &As[q * 2048 + w * 512]);
            GLOAD_LDS(fnh + (size_t)(j0 + q * 32 + srow) * D_DIM + k0 + sseg,
                      &Bs[q * 2048 + w * 512]);
        }
        __syncthreads();
        #pragma unroll
        for (int kk = 0; kk < 2; ++kk) {
            const int swz = ((kk * 4 + grp) ^ (l15 & 7)) * 8;
            half8 aj[4], bi[4];
            #pragma unroll
            for (int jt = 0; jt < 4; ++jt)
                aj[jt] = *(const half8*)&Bs[(wc * 64 + jt * 16 + l15) * 64 + swz];
            #pragma unroll
            for (int it = 0; it < 4; ++it)
                bi[it] = *(const half8*)&As[(wr * 64 + it * 16 + l15) * 64 + swz];
            #pragma unroll
            for (int jt = 0; jt < 4; ++jt)
                #pragma unroll
                for (int it = 0; it < 4; ++it)
                    acc[jt][it] = __builtin_amdgcn_mfma_f32_16x16x32_f16(
                        aj[jt], bi[it], acc[jt][it], 0, 0, 0);
        }
        __syncthreads();
    }

    #pragma unroll
    for (int it = 0; it < 4; ++it) {
        const int row = wr * 64 + it * 16 + l15;
        #pragma unroll
        for (int jt = 0; jt < 4; ++jt) {
            half4 h;
            h.x = (_Float16)(acc[jt][it][0] * INV_T);
            h.y = (_Float16)(acc[jt][it][1] * INV_T);
            h.z = (_Float16)(acc[jt][it][2] * INV_T);
            h.w = (_Float16)(acc[jt][it][3] * INV_T);
            const int g   = wc * 8 + jt * 2 + (grp >> 1);
            const int off = ((g ^ l15) << 4) | ((grp & 1) << 3);
            *(half4*)((char*)lds + row * 256 + off) = h;
        }
    }
    __syncthreads();

    const int lrow8 = t >> 5;
    const int lcol  = t & 31;
    const int gsw   = lcol >> 1;
    const int soff  = (lcol & 1) << 3;
    #pragma unroll
    for (int s = 0; s < 16; ++s) {
        const int r  = s * 8 + lrow8;
        const int i  = i0 + r;
        const int jb = j0 + lcol * 4;
        float4 pmv = *(const float4*)(pm + (size_t)i * N_ROWS + jb);
        float4 nmv = *(const float4*)(nm + (size_t)i * N_ROWS + jb);
        half4 h = *(const half4*)((const char*)lds + r * 256 +
                                  (((gsw ^ (r & 15)) << 4) | soff));
        float cse[4] = {(float)h.x, (float)h.y, (float)h.z, (float)h.w};
        float pme[4] = {pmv.x, pmv.y, pmv.z, pmv.w};
        float nme[4] = {nmv.x, nmv.y, nmv.z, nmv.w};
        float negp = 0.f, posp = 0.f, np = 0.f;
        #pragma unroll
        for (int e = 0; e < 4; ++e) {
            float keep = (i == jb + e) ? 0.f : 1.f;
            float p  = pme[e] * keep;
            float nv = nme[e] * keep;
            negp = fmaf(__expf(cse[e]), nv, negp);
            posp = fmaf(cse[e], p, posp);
            np  += p;
        }
        #pragma unroll
        for (int off = 1; off < 32; off <<= 1) {
            negp += __shfl_xor(negp, off, 64);
            posp += __shfl_xor(posp, off, 64);
            np   += __shfl_xor(np,   off, 64);
        }
        if (lcol == 0) {
            atomicAdd(&accum[i], negp);
            atomicAdd(&accum[N_ROWS + i], posp);
            atomicAdd(&accum[2 * N_ROWS + i], np);
        }
    }
}

// ---------------------------------------------------------------------------
// K3: final reduction over rows -> scalar loss
// ---------------------------------------------------------------------------
__global__ __launch_bounds__(256) void final_k(const float* __restrict__ accum,
                                               float* __restrict__ out) {
    const int t = threadIdx.x;
    float s = 0.f;
    for (int i = t; i < N_ROWS; i += 256) {
        float neg  = accum[i];
        float posc = accum[N_ROWS + i];
        float np   = accum[2 * N_ROWS + i];
        float term = (np > 0.f) ? (posc - np * logf(fmaxf(neg, 1e-30f))) / np : 0.f;
        s += term;
    }
    #pragma unroll
    for (int off = 32; off > 0; off >>= 1) s += __shfl_xor(s, off, 64);
    __shared__ float wsum[4];
    if ((t & 63) == 0) wsum[t >> 6] = s;
    __syncthreads();
    if (t == 0) {
        float tot = wsum[0] + wsum[1] + wsum[2] + wsum[3];
        out[0] = -tot / (float)N_ROWS;
    }
}

// ---------------------------------------------------------------------------
extern "C" void kernel_launch(void* const* d_in, const int* in_sizes, int n_in,
                              void* d_out, int out_size, void* d_ws, size_t ws_size,
                              hipStream_t stream) {
    const float* feat = (const float*)d_in[0];
    const float* pm   = (const float*)d_in[1];
    const float* nm   = (const float*)d_in[2];
    float* out = (float*)d_out;

    _Float16* fnh = (_Float16*)d_ws;                          // 2 MB
    float* accum  = (float*)(fnh + (size_t)N_ROWS * D_DIM);   // 48 KB
    _Float16* cs  = (_Float16*)(accum + 3 * N_ROWS);          // 32 MB

    const size_t need = (size_t)N_ROWS * D_DIM * 2 + 3 * N_ROWS * 4
                      + (size_t)N_ROWS * N_ROWS * 2;

    normalize_k<<<N_ROWS / 4, 256, 0, stream>>>(feat, fnh, accum);

    if (ws_size >= need) {
        dim3 grid(N_ROWS / 128, N_ROWS / 128);
        gemm_cs_k<<<grid, 256, 0, stream>>>(fnh, cs);
        stream_k<<<N_ROWS, 256, 0, stream>>>(cs, pm, nm, accum);
    } else {
        dim3 grid(N_ROWS / 128, N_ROWS / 128);
        fused_k<<<grid, 256, 0, stream>>>(fnh, pm, nm, accum);
    }

    final_k<<<1, 256, 0, stream>>>(accum, out);
}